// Round 4
// baseline (345.183 us; speedup 1.0000x reference)
//
#include <hip/hip_runtime.h>
#include <hip/hip_bf16.h>

typedef __bf16 bf16_t;
typedef __attribute__((ext_vector_type(8))) __bf16 bf16x8;
typedef __attribute__((ext_vector_type(4))) float f32x4;

#define Bn 8
#define Hh 128
#define Ww 128
#define HW 16384

// ---- ws byte-offset layout ----
#define WP1_B   ((size_t)0)          // 25*4*4*64*8 bf16 = 409600 B
#define WP2_B   ((size_t)409600)     // 9*2*4*64*8 bf16  = 73728 B
#define WPO_B   ((size_t)483328)     // 9*2*4*32*8 bf16  = 36864 B
#define WDCN_B  ((size_t)520192)     // dcn B-frags: 18*4*4*16*8 bf16 = 73728 B
#define BIAS_B  ((size_t)667648)     // 224 f32
#define XT_B    ((size_t)668672)     // Xt NHWC bf16 [8][16384][128] = 33554432 B (LIVE until dcn)
#define F1_B    (XT_B + 33554432)    // feat1 [8][16384][64] bf16; OO f32[8][32][16384] aliases after conv2
#define F2_B    (F1_B + 16777216)    // feat2 [8][16384][64] bf16
// total = 67,777,536 B

// ---------------- prep: swizzle weights into MFMA B-fragment order ----------------
__global__ void prep_kernel(const float* __restrict__ w1, const float* __restrict__ w2,
                            const float* __restrict__ woff, const float* __restrict__ wdcn,
                            const float* __restrict__ b1, const float* __restrict__ b2,
                            const float* __restrict__ boff, const float* __restrict__ bdcn,
                            char* __restrict__ wsb) {
    bf16_t* wp1 = (bf16_t*)(wsb + WP1_B);
    bf16_t* wp2 = (bf16_t*)(wsb + WP2_B);
    bf16_t* wpo = (bf16_t*)(wsb + WPO_B);
    bf16_t* wd  = (bf16_t*)(wsb + WDCN_B);
    float*  bias= (float*)(wsb + BIAS_B);
    int tid = blockIdx.x * blockDim.x + threadIdx.x;
    int nt  = gridDim.x * blockDim.x;
    for (int i = tid; i < 25*4*4*64*8; i += nt) {
        int j = i & 7, q = i >> 3;
        int n = q % 64; q /= 64;
        int g = q & 3;  q >>= 2;
        int ck = q & 3; int t = q >> 2;
        int cin = ck*32 + g*8 + j;
        wp1[i] = (bf16_t)w1[(n*128 + cin)*25 + t];
    }
    for (int i = tid; i < 9*2*4*64*8; i += nt) {
        int j = i & 7, q = i >> 3;
        int n = q % 64; q /= 64;
        int g = q & 3;  q >>= 2;
        int ck = q & 1; int t = q >> 1;
        int cin = ck*32 + g*8 + j;
        wp2[i] = (bf16_t)w2[(n*64 + cin)*9 + t];
    }
    for (int i = tid; i < 9*2*4*32*8; i += nt) {
        int j = i & 7, q = i >> 3;
        int n = q & 31; q >>= 5;
        int g = q & 3;  q >>= 2;
        int ck = q & 1; int t = q >> 1;
        int cin = ck*32 + g*8 + j;
        wpo[i] = (n < 27) ? (bf16_t)woff[(n*64 + cin)*9 + t] : (bf16_t)0.f;
    }
    for (int i = tid; i < 18*4*4*16*8; i += nt) {
        int j = i & 7, f = i >> 3;
        int l15 = f & 15; f >>= 4;
        int l4  = f & 3;  f >>= 2;
        int ntl = f & 3;  int kc = f >> 2;
        int kg = kc*32 + l4*8 + j;
        int tap = kg >> 6, c = kg & 63;
        int n = ntl*16 + l15;
        wd[i] = (bf16_t)wdcn[n*576 + c*9 + tap];
    }
    if (tid < 64) { bias[tid] = b1[tid]; bias[64+tid] = b2[tid]; bias[160+tid] = bdcn[tid]; }
    if (tid >= 64 && tid < 96) { int n = tid - 64; bias[128+n] = (n < 27) ? boff[n] : 0.f; }
}

// ---------------- NCHW f32 (Fi||Fe) -> NHWC bf16 Xt[b][p][128] ----------------
// Fused: also writes the f32 Fi copy into Ff[:, 0:64] (removes separate copy_fi
// kernel and its redundant 67 MB read of Fi).
__global__ __launch_bounds__(256) void nhwc_kernel(const float* __restrict__ Fi,
                                                   const float* __restrict__ Fe,
                                                   bf16_t* __restrict__ Xt,
                                                   float* __restrict__ out1) {
    __shared__ bf16_t tile[64][136];
    const int b  = blockIdx.y;
    const int p0 = blockIdx.x * 64;
    const int px = threadIdx.x & 63;
    const int csub = threadIdx.x >> 6;
    for (int ci = 0; ci < 32; ++ci) {
        int c = csub * 32 + ci;
        const float* src = (c < 64) ? (Fi + (((size_t)(b*64 + c)) << 14))
                                    : (Fe + (((size_t)(b*64 + (c-64))) << 14));
        const float v = src[p0 + px];
        tile[px][c] = (bf16_t)v;
        if (c < 64) out1[(((size_t)(b*128 + c)) << 14) + p0 + px] = v;  // Ff Fi-half (f32 NCHW)
    }
    __syncthreads();
    const int px2 = threadIdx.x >> 2;
    const int cc  = (threadIdx.x & 3) * 32;
    bf16x8* dst = (bf16x8*)(Xt + ((size_t)(b*HW) + p0 + px2) * 128 + cc);
    const bf16x8* srcl = (const bf16x8*)(&tile[px2][cc]);
    dst[0] = srcl[0]; dst[1] = srcl[1]; dst[2] = srcl[2]; dst[3] = srcl[3];
}

// ---------------- implicit-GEMM conv, wave tile (MW*16)px x COUTP co ----------------
// Round-4 occupancy fix: previous config (64px/wave, grid 512 blocks) gave only
// 2 blocks/CU -> the 2-barrier stage<->compute structure had no cross-block
// overlap. MW=2 (32px/wave) halves the tile -> grid (4,32,8)=1024 blocks =
// 4 blocks/CU, 16 waves/CU; LDS 23.0/16.3 KB; acc VGPRs halve to 32.
// Block: 4 waves, wave w = output row (h0+w), px w0..w0+MW*16-1, all COUTP couts.
// LDS halo: [HR rows][HC cols][32ch] per K-chunk, ch-stride padded to 40 elems.
template <int CIN_, int KS, int COUTP, int MW, bool LEAKY, bool OUTF32, bool OFFS>
__global__ __launch_bounds__(256, 4) void conv_mfma(const bf16_t* __restrict__ Xt,
                                                    const bf16_t* __restrict__ Wp,
                                                    const float* __restrict__ bias,
                                                    bf16_t* __restrict__ outb,
                                                    float* __restrict__ outf,
                                                    float* __restrict__ out0) {
    constexpr int PXW = MW * 16;           // px per wave
    constexpr int PAD = KS / 2;
    constexpr int HR  = 4 + KS - 1;        // 8 (KS=5) / 6 (KS=3)
    constexpr int HC  = PXW + KS - 1;      // 36 / 34
    constexpr int NC  = CIN_ / 32;
    constexpr int NT  = COUTP / 16;        // cout 16-tiles per wave
    __shared__ bf16_t stg[HR * HC * 40];   // 23.0 KB / 16.3 KB

    const int tid  = threadIdx.x;
    const int lane = tid & 63;
    const int wid  = tid >> 6;             // wave = output row within block
    const int b    = blockIdx.z;
    const int h0   = blockIdx.y * 4;
    const int w0   = blockIdx.x * PXW;
    const int l15  = lane & 15;
    const int l4   = lane >> 4;

    f32x4 acc[MW][NT];
#pragma unroll
    for (int m = 0; m < MW; ++m)
#pragma unroll
        for (int nt = 0; nt < NT; ++nt)
#pragma unroll
            for (int r = 0; r < 4; ++r) acc[m][nt][r] = 0.f;

    const bf16_t Z0 = (bf16_t)0.f;
    const bf16x8 zv = {Z0, Z0, Z0, Z0, Z0, Z0, Z0, Z0};
    const bf16x8* wpt = (const bf16x8*)Wp;

    for (int ck = 0; ck < NC; ++ck) {
        for (int s = tid; s < HR * HC; s += 256) {
            const int srow = s / HC, scol = s % HC;
            const int gh = h0 - PAD + srow, gw = w0 - PAD + scol;
            bf16x8 v0 = zv, v1 = zv, v2 = zv, v3 = zv;
            if (((unsigned)gh < 128u) && ((unsigned)gw < 128u)) {
                const bf16x8* gp = (const bf16x8*)(Xt + (((size_t)(b*HW) + (gh << 7) + gw)) * CIN_ + ck * 32);
                v0 = gp[0]; v1 = gp[1]; v2 = gp[2]; v3 = gp[3];
            }
            bf16x8* ldst = (bf16x8*)(&stg[s * 40]);
            ldst[0] = v0; ldst[1] = v1; ldst[2] = v2; ldst[3] = v3;
        }
        __syncthreads();
        int t = 0;
#pragma unroll
        for (int dy = 0; dy < KS; ++dy) {
#pragma unroll
            for (int dx = 0; dx < KS; ++dx, ++t) {
                bf16x8 a[MW];
#pragma unroll
                for (int m = 0; m < MW; ++m)
                    a[m] = *(const bf16x8*)(&stg[((wid + dy) * HC + (m * 16 + l15 + dx)) * 40 + l4 * 8]);
                bf16x8 bb[NT];
#pragma unroll
                for (int nt = 0; nt < NT; ++nt)
                    bb[nt] = wpt[((size_t)((t * NC + ck) * 4 + l4)) * COUTP + nt * 16 + l15];
#pragma unroll
                for (int m = 0; m < MW; ++m)
#pragma unroll
                    for (int nt = 0; nt < NT; ++nt)
                        acc[m][nt] = __builtin_amdgcn_mfma_f32_16x16x32_bf16(a[m], bb[nt], acc[m][nt], 0, 0, 0);
            }
        }
        __syncthreads();
    }

    // epilogue: C/D 16x16: col(cout) = l15, row(px) = l4*4 + r
    const int hrow = h0 + wid;
#pragma unroll
    for (int m = 0; m < MW; ++m) {
#pragma unroll
        for (int nt = 0; nt < NT; ++nt) {
            const int n = nt * 16 + l15;
            const float bs = bias[n];
#pragma unroll
            for (int r = 0; r < 4; ++r) {
                const int px = w0 + m * 16 + l4 * 4 + r;
                float v = acc[m][nt][r] + bs;
                if (LEAKY) v = (v >= 0.f) ? v : 0.1f * v;
                const size_t pix = (size_t)(hrow << 7) + px;
                if (OUTF32) outf[(((size_t)(b * COUTP + n)) << 14) + pix] = v;         // NCHW f32
                else        outb[(((size_t)(b * HW)) + pix) * COUTP + n] = (bf16_t)v;  // NHWC bf16
                if (OFFS) {
                    if (n < 18) out0[(((size_t)(b * 18 + n)) << 14) + pix] = v;
                }
            }
        }
    }
}

// ---------------- DCNv2 via MFMA ----------------
// Rounds 0/2/3 established a ~90us wall invariant to structure, occupancy
// (21->38%) and data placement (FETCH 135->15.5 MB): bound by scattered-gather
// address/segment throughput (9.4M unique 64B segments, inherent to per-px
// bilinear sampling). Keeping the round-3 variant (lowest traffic: OO-hoist +
// 1-deep pipeline + XCD-batch pinning).
__global__ __launch_bounds__(256, 4) void dcn_mfma(const bf16_t* __restrict__ Xt,
                                                   const float* __restrict__ OO,
                                                   const bf16_t* __restrict__ Wd,
                                                   const float* __restrict__ bias,
                                                   float* __restrict__ out1) {
    const int tid  = threadIdx.x;
    const int lane = tid & 63;
    const int wave = tid >> 6;
    const int l15  = lane & 15;
    const int l4   = lane >> 4;
    const int blk  = blockIdx.x;
    const int b    = blk & 7;                      // XCD-pinned batch
    const int p0   = (blk >> 3) * 64 + wave * 16;

    f32x4 acc[4];
#pragma unroll
    for (int nt = 0; nt < 4; ++nt) {
        const float bs = bias[nt * 16 + l15];
        acc[nt][0] = bs; acc[nt][1] = bs; acc[nt][2] = bs; acc[nt][3] = bs;
    }

    const bf16_t* feb = Xt + ((size_t)(b * HW)) * 128 + 64;
    const bf16x8* Wdv = (const bf16x8*)Wd;

    const int p = p0 + l15;
    const int h = p >> 7, w = p & 127;
    const size_t oobase = (((size_t)(b * 32)) << 14) + p;
    const int c0 = l4 * 8;            // cc=0 channel offset within Fe slice
    const int c1 = 32 + l4 * 8;       // cc=1

    // ---- prologue: all 27 OO loads (independent), precompute y/x/m per tap ----
    float ys[9], xs[9], ms[9];
#pragma unroll
    for (int k = 0; k < 9; ++k) {
        const float o1v = OO[oobase + ((size_t)k << 14)];
        const float o2v = OO[oobase + ((size_t)(9 + k) << 14)];
        const float mlv = OO[oobase + ((size_t)(18 + k) << 14)];
        ys[k] = (float)(h - 1 + (k / 3)) + o1v;
        xs[k] = (float)(w - 1 + (k % 3)) + o2v;
        ms[k] = 1.f / (1.f + __expf(-mlv));
    }

    // pipeline state: slot = step parity (cc). g = in-flight gathers, wq = weights.
    bf16x8 g[2][4];
    float  wq[2][4];
    int    toff[4];

#define DCN_ISSUE_EVEN(k)                                                        \
    do {                                                                         \
        const float yk = ys[(k)], xk = xs[(k)];                                  \
        const float y0f = floorf(yk), x0f = floorf(xk);                          \
        const float fy = yk - y0f, fx = xk - x0f;                                \
        const int y0 = (int)y0f, x0 = (int)x0f;                                  \
        const bool vy0 = (unsigned)y0 < 128u;                                    \
        const bool vy1 = (unsigned)(y0 + 1) < 128u;                              \
        const bool vx0 = (unsigned)x0 < 128u;                                    \
        const bool vx1 = (unsigned)(x0 + 1) < 128u;                              \
        const int y0c = min(max(y0, 0), 127), y1c = min(max(y0 + 1, 0), 127);    \
        const int x0c = min(max(x0, 0), 127), x1c = min(max(x0 + 1, 0), 127);    \
        const float mk = ms[(k)];                                                \
        float a00 = (1.f - fy) * (1.f - fx) * mk; a00 = (vy0 && vx0) ? a00 : 0.f;\
        float a01 = (1.f - fy) * fx * mk;         a01 = (vy0 && vx1) ? a01 : 0.f;\
        float a10 = fy * (1.f - fx) * mk;         a10 = (vy1 && vx0) ? a10 : 0.f;\
        float a11 = fy * fx * mk;                 a11 = (vy1 && vx1) ? a11 : 0.f;\
        wq[0][0] = a00; wq[0][1] = a01; wq[0][2] = a10; wq[0][3] = a11;          \
        toff[0] = (y0c << 7) + x0c; toff[1] = (y0c << 7) + x1c;                  \
        toff[2] = (y1c << 7) + x0c; toff[3] = (y1c << 7) + x1c;                  \
        g[0][0] = *(const bf16x8*)(feb + (((size_t)toff[0]) << 7) + c0);         \
        g[0][1] = *(const bf16x8*)(feb + (((size_t)toff[1]) << 7) + c0);         \
        g[0][2] = *(const bf16x8*)(feb + (((size_t)toff[2]) << 7) + c0);         \
        g[0][3] = *(const bf16x8*)(feb + (((size_t)toff[3]) << 7) + c0);         \
    } while (0)

#define DCN_ISSUE_ODD()                                                          \
    do {                                                                         \
        wq[1][0] = wq[0][0]; wq[1][1] = wq[0][1];                                \
        wq[1][2] = wq[0][2]; wq[1][3] = wq[0][3];                                \
        g[1][0] = *(const bf16x8*)(feb + (((size_t)toff[0]) << 7) + c1);         \
        g[1][1] = *(const bf16x8*)(feb + (((size_t)toff[1]) << 7) + c1);         \
        g[1][2] = *(const bf16x8*)(feb + (((size_t)toff[2]) << 7) + c1);         \
        g[1][3] = *(const bf16x8*)(feb + (((size_t)toff[3]) << 7) + c1);         \
    } while (0)

#define DCN_CONSUME(s)                                                           \
    do {                                                                         \
        bf16x8 af;                                                               \
        _Pragma("unroll")                                                        \
        for (int j = 0; j < 8; ++j)                                              \
            af[j] = (bf16_t)(wq[(s) & 1][0] * (float)g[(s) & 1][0][j]            \
                           + wq[(s) & 1][1] * (float)g[(s) & 1][1][j]            \
                           + wq[(s) & 1][2] * (float)g[(s) & 1][2][j]            \
                           + wq[(s) & 1][3] * (float)g[(s) & 1][3][j]);          \
        _Pragma("unroll")                                                        \
        for (int nt = 0; nt < 4; ++nt) {                                         \
            const bf16x8 bfr = Wdv[(((s) * 4 + nt) * 4 + l4) * 16 + l15];        \
            acc[nt] = __builtin_amdgcn_mfma_f32_16x16x32_bf16(af, bfr, acc[nt], 0, 0, 0); \
        }                                                                        \
    } while (0)

    DCN_ISSUE_EVEN(0);
#pragma unroll
    for (int s = 0; s < 18; ++s) {
        if (s + 1 < 18) {
            if ((s + 1) & 1) DCN_ISSUE_ODD();
            else             DCN_ISSUE_EVEN((s + 1) >> 1);
        }
        DCN_CONSUME(s);
    }

#undef DCN_ISSUE_EVEN
#undef DCN_ISSUE_ODD
#undef DCN_CONSUME

#pragma unroll
    for (int nt = 0; nt < 4; ++nt) {
        const int o = nt * 16 + l15;
#pragma unroll
        for (int r = 0; r < 4; ++r) {
            const int px = p0 + l4 * 4 + r;
            out1[(((size_t)(b * 128 + 64 + o)) << 14) + px] = acc[nt][r];
        }
    }
}

extern "C" void kernel_launch(void* const* d_in, const int* in_sizes, int n_in,
                              void* d_out, int out_size, void* d_ws, size_t ws_size,
                              hipStream_t stream) {
    const float* Fi    = (const float*)d_in[0];
    const float* Fe    = (const float*)d_in[1];
    const float* w1    = (const float*)d_in[2];
    const float* b1    = (const float*)d_in[3];
    const float* w2    = (const float*)d_in[4];
    const float* b2    = (const float*)d_in[5];
    const float* w_off = (const float*)d_in[6];
    const float* b_off = (const float*)d_in[7];
    const float* w_dcn = (const float*)d_in[8];
    const float* b_dcn = (const float*)d_in[9];

    char* wsb = (char*)d_ws;
    bf16_t* wp1   = (bf16_t*)(wsb + WP1_B);
    bf16_t* wp2   = (bf16_t*)(wsb + WP2_B);
    bf16_t* wpo   = (bf16_t*)(wsb + WPO_B);
    bf16_t* wdcnf = (bf16_t*)(wsb + WDCN_B);
    float*  bias  = (float*)(wsb + BIAS_B);
    bf16_t* Xt    = (bf16_t*)(wsb + XT_B);
    bf16_t* feat1 = (bf16_t*)(wsb + F1_B);
    bf16_t* feat2 = (bf16_t*)(wsb + F2_B);
    float*  OO    = (float*)(wsb + F1_B);    // NCHW [b][32][HW]; alias: feat1 dead after conv2

    float* out0 = (float*)d_out;                   // offset_out [8,18,128,128]
    float* out1 = out0 + (size_t)Bn * 18 * HW;     // Ff [8,128,128,128]

    prep_kernel<<<256, 256, 0, stream>>>(w1, w2, w_off, w_dcn, b1, b2, b_off, b_dcn, wsb);

    nhwc_kernel<<<dim3(256, 8), 256, 0, stream>>>(Fi, Fe, Xt, out1);

    conv_mfma<128, 5, 64, 2, true, false, false>
        <<<dim3(4, 32, 8), 256, 0, stream>>>(Xt, wp1, bias, feat1, nullptr, nullptr);

    conv_mfma<64, 3, 64, 2, true, false, false>
        <<<dim3(4, 32, 8), 256, 0, stream>>>(feat1, wp2, bias + 64, feat2, nullptr, nullptr);

    conv_mfma<64, 3, 32, 2, false, true, true>
        <<<dim3(4, 32, 8), 256, 0, stream>>>(feat2, wpo, bias + 128, nullptr, OO, out0);

    dcn_mfma<<<2048, 256, 0, stream>>>(Xt, OO, wdcnf, bias + 160, out1);
}

// Round 5
// 335.631 us; speedup vs baseline: 1.0285x; 1.0285x over previous
//
#include <hip/hip_runtime.h>
#include <hip/hip_bf16.h>

typedef __bf16 bf16_t;
typedef __attribute__((ext_vector_type(8))) __bf16 bf16x8;
typedef __attribute__((ext_vector_type(4))) float f32x4;

#define Bn 8
#define Hh 128
#define Ww 128
#define HW 16384

// ---- ws byte-offset layout ----
#define WP1_B   ((size_t)0)          // 25*4*4*64*8 bf16 = 409600 B
#define WP2_B   ((size_t)409600)     // 9*2*4*64*8 bf16  = 73728 B
#define WPO_B   ((size_t)483328)     // 9*2*4*32*8 bf16  = 36864 B
#define WDCN_B  ((size_t)520192)     // dcn B-frags: 18*4*4*16*8 bf16 = 73728 B
#define BIAS_B  ((size_t)667648)     // 224 f32
#define XT_B    ((size_t)668672)     // Xt NHWC bf16 [8][16384][128] = 33554432 B (LIVE until dcn)
#define F1_B    (XT_B + 33554432)    // feat1 [8][16384][64] bf16; OO f32[8][32][16384] aliases after conv2
#define F2_B    (F1_B + 16777216)    // feat2 [8][16384][64] bf16
// total = 67,777,536 B

// ---------------- prep: swizzle weights into MFMA B-fragment order ----------------
__global__ void prep_kernel(const float* __restrict__ w1, const float* __restrict__ w2,
                            const float* __restrict__ woff, const float* __restrict__ wdcn,
                            const float* __restrict__ b1, const float* __restrict__ b2,
                            const float* __restrict__ boff, const float* __restrict__ bdcn,
                            char* __restrict__ wsb) {
    bf16_t* wp1 = (bf16_t*)(wsb + WP1_B);
    bf16_t* wp2 = (bf16_t*)(wsb + WP2_B);
    bf16_t* wpo = (bf16_t*)(wsb + WPO_B);
    bf16_t* wd  = (bf16_t*)(wsb + WDCN_B);
    float*  bias= (float*)(wsb + BIAS_B);
    int tid = blockIdx.x * blockDim.x + threadIdx.x;
    int nt  = gridDim.x * blockDim.x;
    for (int i = tid; i < 25*4*4*64*8; i += nt) {
        int j = i & 7, q = i >> 3;
        int n = q % 64; q /= 64;
        int g = q & 3;  q >>= 2;
        int ck = q & 3; int t = q >> 2;
        int cin = ck*32 + g*8 + j;
        wp1[i] = (bf16_t)w1[(n*128 + cin)*25 + t];
    }
    for (int i = tid; i < 9*2*4*64*8; i += nt) {
        int j = i & 7, q = i >> 3;
        int n = q % 64; q /= 64;
        int g = q & 3;  q >>= 2;
        int ck = q & 1; int t = q >> 1;
        int cin = ck*32 + g*8 + j;
        wp2[i] = (bf16_t)w2[(n*64 + cin)*9 + t];
    }
    for (int i = tid; i < 9*2*4*32*8; i += nt) {
        int j = i & 7, q = i >> 3;
        int n = q & 31; q >>= 5;
        int g = q & 3;  q >>= 2;
        int ck = q & 1; int t = q >> 1;
        int cin = ck*32 + g*8 + j;
        wpo[i] = (n < 27) ? (bf16_t)woff[(n*64 + cin)*9 + t] : (bf16_t)0.f;
    }
    for (int i = tid; i < 18*4*4*16*8; i += nt) {
        int j = i & 7, f = i >> 3;
        int l15 = f & 15; f >>= 4;
        int l4  = f & 3;  f >>= 2;
        int ntl = f & 3;  int kc = f >> 2;
        int kg = kc*32 + l4*8 + j;
        int tap = kg >> 6, c = kg & 63;
        int n = ntl*16 + l15;
        wd[i] = (bf16_t)wdcn[n*576 + c*9 + tap];
    }
    if (tid < 64) { bias[tid] = b1[tid]; bias[64+tid] = b2[tid]; bias[160+tid] = bdcn[tid]; }
    if (tid >= 64 && tid < 96) { int n = tid - 64; bias[128+n] = (n < 27) ? boff[n] : 0.f; }
}

// ---------------- NCHW f32 (Fi||Fe) -> NHWC bf16 Xt[b][p][128] ----------------
// Fused: also writes the f32 Fi copy into Ff[:, 0:64] (removes separate copy_fi
// kernel and its redundant 67 MB read of Fi).
__global__ __launch_bounds__(256) void nhwc_kernel(const float* __restrict__ Fi,
                                                   const float* __restrict__ Fe,
                                                   bf16_t* __restrict__ Xt,
                                                   float* __restrict__ out1) {
    __shared__ bf16_t tile[64][136];
    const int b  = blockIdx.y;
    const int p0 = blockIdx.x * 64;
    const int px = threadIdx.x & 63;
    const int csub = threadIdx.x >> 6;
    for (int ci = 0; ci < 32; ++ci) {
        int c = csub * 32 + ci;
        const float* src = (c < 64) ? (Fi + (((size_t)(b*64 + c)) << 14))
                                    : (Fe + (((size_t)(b*64 + (c-64))) << 14));
        const float v = src[p0 + px];
        tile[px][c] = (bf16_t)v;
        if (c < 64) out1[(((size_t)(b*128 + c)) << 14) + p0 + px] = v;  // Ff Fi-half (f32 NCHW)
    }
    __syncthreads();
    const int px2 = threadIdx.x >> 2;
    const int cc  = (threadIdx.x & 3) * 32;
    bf16x8* dst = (bf16x8*)(Xt + ((size_t)(b*HW) + p0 + px2) * 128 + cc);
    const bf16x8* srcl = (const bf16x8*)(&tile[px2][cc]);
    dst[0] = srcl[0]; dst[1] = srcl[1]; dst[2] = srcl[2]; dst[3] = srcl[3];
}

// ---------------- implicit-GEMM conv, wave tile 64px x 64co ----------------
// Round-5: reverted to the round-0/3 geometry (64px/wave, grid (2,32,8),
// plain launch_bounds(256)) -- round 4's MW=2 halving REGRESSED (~+11us total:
// doubled B-frag loads + per-block staging overhead outran the occupancy gain).
// Block: 4 waves, wave w = output row (h0+w), px w0..w0+63, all COUTP couts.
// LDS halo: [HR rows][HC cols][32ch] per K-chunk, ch-stride padded to 40 elems.
template <int CIN_, int KS, int COUTP, bool LEAKY, bool OUTF32, bool OFFS>
__global__ __launch_bounds__(256) void conv_mfma(const bf16_t* __restrict__ Xt,
                                                 const bf16_t* __restrict__ Wp,
                                                 const float* __restrict__ bias,
                                                 bf16_t* __restrict__ outb,
                                                 float* __restrict__ outf,
                                                 float* __restrict__ out0) {
    constexpr int PAD = KS / 2;
    constexpr int HR  = 4 + KS - 1;        // 8 (KS=5) / 6 (KS=3)
    constexpr int HC  = 64 + KS - 1;       // 68 / 66
    constexpr int NC  = CIN_ / 32;
    constexpr int NT  = COUTP / 16;        // cout 16-tiles per wave
    __shared__ bf16_t stg[HR * HC * 40];   // 43.5 KB / 31.7 KB

    const int tid  = threadIdx.x;
    const int lane = tid & 63;
    const int wid  = tid >> 6;             // wave = output row within block
    const int b    = blockIdx.z;
    const int h0   = blockIdx.y * 4;
    const int w0   = blockIdx.x * 64;
    const int l15  = lane & 15;
    const int l4   = lane >> 4;

    f32x4 acc[4][NT];
#pragma unroll
    for (int m = 0; m < 4; ++m)
#pragma unroll
        for (int nt = 0; nt < NT; ++nt)
#pragma unroll
            for (int r = 0; r < 4; ++r) acc[m][nt][r] = 0.f;

    const bf16_t Z0 = (bf16_t)0.f;
    const bf16x8 zv = {Z0, Z0, Z0, Z0, Z0, Z0, Z0, Z0};
    const bf16x8* wpt = (const bf16x8*)Wp;

    for (int ck = 0; ck < NC; ++ck) {
        for (int s = tid; s < HR * HC; s += 256) {
            const int srow = s / HC, scol = s % HC;
            const int gh = h0 - PAD + srow, gw = w0 - PAD + scol;
            bf16x8 v0 = zv, v1 = zv, v2 = zv, v3 = zv;
            if (((unsigned)gh < 128u) && ((unsigned)gw < 128u)) {
                const bf16x8* gp = (const bf16x8*)(Xt + (((size_t)(b*HW) + (gh << 7) + gw)) * CIN_ + ck * 32);
                v0 = gp[0]; v1 = gp[1]; v2 = gp[2]; v3 = gp[3];
            }
            bf16x8* ldst = (bf16x8*)(&stg[s * 40]);
            ldst[0] = v0; ldst[1] = v1; ldst[2] = v2; ldst[3] = v3;
        }
        __syncthreads();
        int t = 0;
#pragma unroll
        for (int dy = 0; dy < KS; ++dy) {
#pragma unroll
            for (int dx = 0; dx < KS; ++dx, ++t) {
                bf16x8 a[4];
#pragma unroll
                for (int m = 0; m < 4; ++m)
                    a[m] = *(const bf16x8*)(&stg[((wid + dy) * HC + (m * 16 + l15 + dx)) * 40 + l4 * 8]);
                bf16x8 bb[NT];
#pragma unroll
                for (int nt = 0; nt < NT; ++nt)
                    bb[nt] = wpt[((size_t)((t * NC + ck) * 4 + l4)) * COUTP + nt * 16 + l15];
#pragma unroll
                for (int m = 0; m < 4; ++m)
#pragma unroll
                    for (int nt = 0; nt < NT; ++nt)
                        acc[m][nt] = __builtin_amdgcn_mfma_f32_16x16x32_bf16(a[m], bb[nt], acc[m][nt], 0, 0, 0);
            }
        }
        __syncthreads();
    }

    // epilogue: C/D 16x16: col(cout) = l15, row(px) = l4*4 + r
    const int hrow = h0 + wid;
#pragma unroll
    for (int m = 0; m < 4; ++m) {
#pragma unroll
        for (int nt = 0; nt < NT; ++nt) {
            const int n = nt * 16 + l15;
            const float bs = bias[n];
#pragma unroll
            for (int r = 0; r < 4; ++r) {
                const int px = w0 + m * 16 + l4 * 4 + r;
                float v = acc[m][nt][r] + bs;
                if (LEAKY) v = (v >= 0.f) ? v : 0.1f * v;
                const size_t pix = (size_t)(hrow << 7) + px;
                if (OUTF32) outf[(((size_t)(b * COUTP + n)) << 14) + pix] = v;         // NCHW f32
                else        outb[(((size_t)(b * HW)) + pix) * COUTP + n] = (bf16_t)v;  // NHWC bf16
                if (OFFS) {
                    if (n < 18) out0[(((size_t)(b * 18 + n)) << 14) + pix] = v;
                }
            }
        }
    }
}

// ---------------- DCNv2 via MFMA ----------------
// Round-5: 4-slot ring software pipeline, issue-ahead depth 3 (16 gathers in
// flight per wave). Rationale: 91us sits 3x above the XCD-L2 request-BW floor
// (~31us) -> concurrency-starved. Need ~200 outstanding req/CU; round-3's
// 1-deep pipeline gave ~96 (8/wave x 12 waves). Depth-3 doubles in-flight.
// VGPR ~150 -> launch_bounds(256,3) (~170 cap); occupancy stays ~3 waves/SIMD
// (what rounds 2-4 measured anyway). Tripwire: WRITE_SIZE must stay ~32.8 MB.
__global__ __launch_bounds__(256, 3) void dcn_mfma(const bf16_t* __restrict__ Xt,
                                                   const float* __restrict__ OO,
                                                   const bf16_t* __restrict__ Wd,
                                                   const float* __restrict__ bias,
                                                   float* __restrict__ out1) {
    const int tid  = threadIdx.x;
    const int lane = tid & 63;
    const int wave = tid >> 6;
    const int l15  = lane & 15;
    const int l4   = lane >> 4;
    const int blk  = blockIdx.x;
    const int b    = blk & 7;                      // XCD-pinned batch
    const int p0   = (blk >> 3) * 64 + wave * 16;

    f32x4 acc[4];
#pragma unroll
    for (int nt = 0; nt < 4; ++nt) {
        const float bs = bias[nt * 16 + l15];
        acc[nt][0] = bs; acc[nt][1] = bs; acc[nt][2] = bs; acc[nt][3] = bs;
    }

    const bf16_t* feb = Xt + ((size_t)(b * HW)) * 128 + 64;
    const bf16x8* Wdv = (const bf16x8*)Wd;

    const int p = p0 + l15;
    const int h = p >> 7, w = p & 127;
    const size_t oobase = (((size_t)(b * 32)) << 14) + p;
    const int c0 = l4 * 8;            // cc=0 channel offset within Fe slice
    const int c1 = 32 + l4 * 8;       // cc=1

    // ---- prologue: all 27 OO loads (independent), precompute y/x/m per tap ----
    float ys[9], xs[9], ms[9];
#pragma unroll
    for (int k = 0; k < 9; ++k) {
        const float o1v = OO[oobase + ((size_t)k << 14)];
        const float o2v = OO[oobase + ((size_t)(9 + k) << 14)];
        const float mlv = OO[oobase + ((size_t)(18 + k) << 14)];
        ys[k] = (float)(h - 1 + (k / 3)) + o1v;
        xs[k] = (float)(w - 1 + (k % 3)) + o2v;
        ms[k] = 1.f / (1.f + __expf(-mlv));
    }

    // ring pipeline state: slot = step & 3. g = in-flight gathers, wq = weights.
    // toff single-buffered: issues are sequential (E(k) immediately followed by
    // O(k) in issue order), so each tap's toff is consumed before overwrite.
    bf16x8 g[4][4];
    float  wq[4][4];
    int    toff[4];

#define DCN_ISSUE_E(s)                                                           \
    do {                                                                         \
        const int k_ = (s) >> 1, sl_ = (s) & 3;                                  \
        const float yk = ys[k_], xk = xs[k_];                                    \
        const float y0f = floorf(yk), x0f = floorf(xk);                          \
        const float fy = yk - y0f, fx = xk - x0f;                                \
        const int y0 = (int)y0f, x0 = (int)x0f;                                  \
        const bool vy0 = (unsigned)y0 < 128u;                                    \
        const bool vy1 = (unsigned)(y0 + 1) < 128u;                              \
        const bool vx0 = (unsigned)x0 < 128u;                                    \
        const bool vx1 = (unsigned)(x0 + 1) < 128u;                              \
        const int y0c = min(max(y0, 0), 127), y1c = min(max(y0 + 1, 0), 127);    \
        const int x0c = min(max(x0, 0), 127), x1c = min(max(x0 + 1, 0), 127);    \
        const float mk = ms[k_];                                                 \
        float a00 = (1.f - fy) * (1.f - fx) * mk; a00 = (vy0 && vx0) ? a00 : 0.f;\
        float a01 = (1.f - fy) * fx * mk;         a01 = (vy0 && vx1) ? a01 : 0.f;\
        float a10 = fy * (1.f - fx) * mk;         a10 = (vy1 && vx0) ? a10 : 0.f;\
        float a11 = fy * fx * mk;                 a11 = (vy1 && vx1) ? a11 : 0.f;\
        wq[sl_][0] = a00; wq[sl_][1] = a01; wq[sl_][2] = a10; wq[sl_][3] = a11;  \
        toff[0] = (y0c << 7) + x0c; toff[1] = (y0c << 7) + x1c;                  \
        toff[2] = (y1c << 7) + x0c; toff[3] = (y1c << 7) + x1c;                  \
        g[sl_][0] = *(const bf16x8*)(feb + (((size_t)toff[0]) << 7) + c0);       \
        g[sl_][1] = *(const bf16x8*)(feb + (((size_t)toff[1]) << 7) + c0);       \
        g[sl_][2] = *(const bf16x8*)(feb + (((size_t)toff[2]) << 7) + c0);       \
        g[sl_][3] = *(const bf16x8*)(feb + (((size_t)toff[3]) << 7) + c0);       \
    } while (0)

#define DCN_ISSUE_O(s)                                                           \
    do {                                                                         \
        const int sl_ = (s) & 3, pe_ = ((s) - 1) & 3;                            \
        wq[sl_][0] = wq[pe_][0]; wq[sl_][1] = wq[pe_][1];                        \
        wq[sl_][2] = wq[pe_][2]; wq[sl_][3] = wq[pe_][3];                        \
        g[sl_][0] = *(const bf16x8*)(feb + (((size_t)toff[0]) << 7) + c1);       \
        g[sl_][1] = *(const bf16x8*)(feb + (((size_t)toff[1]) << 7) + c1);       \
        g[sl_][2] = *(const bf16x8*)(feb + (((size_t)toff[2]) << 7) + c1);       \
        g[sl_][3] = *(const bf16x8*)(feb + (((size_t)toff[3]) << 7) + c1);       \
    } while (0)

#define DCN_CONSUME(s)                                                           \
    do {                                                                         \
        const int sl_ = (s) & 3;                                                 \
        bf16x8 af;                                                               \
        _Pragma("unroll")                                                        \
        for (int j = 0; j < 8; ++j)                                              \
            af[j] = (bf16_t)(wq[sl_][0] * (float)g[sl_][0][j]                    \
                           + wq[sl_][1] * (float)g[sl_][1][j]                    \
                           + wq[sl_][2] * (float)g[sl_][2][j]                    \
                           + wq[sl_][3] * (float)g[sl_][3][j]);                  \
        _Pragma("unroll")                                                        \
        for (int nt = 0; nt < 4; ++nt) {                                         \
            const bf16x8 bfr = Wdv[(((s) * 4 + nt) * 4 + l4) * 16 + l15];        \
            acc[nt] = __builtin_amdgcn_mfma_f32_16x16x32_bf16(af, bfr, acc[nt], 0, 0, 0); \
        }                                                                        \
    } while (0)

    // fill the pipe: steps 0,1,2 in flight before first consume
    DCN_ISSUE_E(0);
    DCN_ISSUE_O(1);
    DCN_ISSUE_E(2);
#pragma unroll
    for (int s = 0; s < 18; ++s) {
        if (s + 3 < 18) {
            if ((s + 3) & 1) DCN_ISSUE_O(s + 3);
            else             DCN_ISSUE_E(s + 3);
        }
        DCN_CONSUME(s);
    }

#undef DCN_ISSUE_E
#undef DCN_ISSUE_O
#undef DCN_CONSUME

#pragma unroll
    for (int nt = 0; nt < 4; ++nt) {
        const int o = nt * 16 + l15;
#pragma unroll
        for (int r = 0; r < 4; ++r) {
            const int px = p0 + l4 * 4 + r;
            out1[(((size_t)(b * 128 + 64 + o)) << 14) + px] = acc[nt][r];
        }
    }
}

extern "C" void kernel_launch(void* const* d_in, const int* in_sizes, int n_in,
                              void* d_out, int out_size, void* d_ws, size_t ws_size,
                              hipStream_t stream) {
    const float* Fi    = (const float*)d_in[0];
    const float* Fe    = (const float*)d_in[1];
    const float* w1    = (const float*)d_in[2];
    const float* b1    = (const float*)d_in[3];
    const float* w2    = (const float*)d_in[4];
    const float* b2    = (const float*)d_in[5];
    const float* w_off = (const float*)d_in[6];
    const float* b_off = (const float*)d_in[7];
    const float* w_dcn = (const float*)d_in[8];
    const float* b_dcn = (const float*)d_in[9];

    char* wsb = (char*)d_ws;
    bf16_t* wp1   = (bf16_t*)(wsb + WP1_B);
    bf16_t* wp2   = (bf16_t*)(wsb + WP2_B);
    bf16_t* wpo   = (bf16_t*)(wsb + WPO_B);
    bf16_t* wdcnf = (bf16_t*)(wsb + WDCN_B);
    float*  bias  = (float*)(wsb + BIAS_B);
    bf16_t* Xt    = (bf16_t*)(wsb + XT_B);
    bf16_t* feat1 = (bf16_t*)(wsb + F1_B);
    bf16_t* feat2 = (bf16_t*)(wsb + F2_B);
    float*  OO    = (float*)(wsb + F1_B);    // NCHW [b][32][HW]; alias: feat1 dead after conv2

    float* out0 = (float*)d_out;                   // offset_out [8,18,128,128]
    float* out1 = out0 + (size_t)Bn * 18 * HW;     // Ff [8,128,128,128]

    prep_kernel<<<256, 256, 0, stream>>>(w1, w2, w_off, w_dcn, b1, b2, b_off, b_dcn, wsb);

    nhwc_kernel<<<dim3(256, 8), 256, 0, stream>>>(Fi, Fe, Xt, out1);

    conv_mfma<128, 5, 64, true, false, false>
        <<<dim3(2, 32, 8), 256, 0, stream>>>(Xt, wp1, bias, feat1, nullptr, nullptr);

    conv_mfma<64, 3, 64, true, false, false>
        <<<dim3(2, 32, 8), 256, 0, stream>>>(feat1, wp2, bias + 64, feat2, nullptr, nullptr);

    conv_mfma<64, 3, 32, false, true, true>
        <<<dim3(2, 32, 8), 256, 0, stream>>>(feat2, wpo, bias + 128, nullptr, OO, out0);

    dcn_mfma<<<2048, 256, 0, stream>>>(Xt, OO, wdcnf, bias + 160, out1);
}

// Round 6
// 305.890 us; speedup vs baseline: 1.1285x; 1.0972x over previous
//
#include <hip/hip_runtime.h>
#include <hip/hip_bf16.h>

typedef __bf16 bf16_t;
typedef __attribute__((ext_vector_type(8))) __bf16 bf16x8;
typedef __attribute__((ext_vector_type(4))) float f32x4;

#define Bn 8
#define Hh 128
#define Ww 128
#define HW 16384

// ---- ws byte-offset layout ----
#define WP1_B   ((size_t)0)          // 25*4*4*64*8 bf16 = 409600 B
#define WP2_B   ((size_t)409600)     // 9*2*4*64*8 bf16  = 73728 B
#define WPO_B   ((size_t)483328)     // 9*2*4*32*8 bf16  = 36864 B
#define WDCN_B  ((size_t)520192)     // dcn B-frags: 18*4*4*16*8 bf16 = 73728 B
#define BIAS_B  ((size_t)667648)     // 224 f32
#define XT_B    ((size_t)668672)     // Xt NHWC bf16 [8][16384][128] = 33554432 B (LIVE until dcn)
#define F1_B    (XT_B + 33554432)    // feat1 [8][16384][64] bf16; OO f32[8][32][16384] aliases after conv2
#define F2_B    (F1_B + 16777216)    // feat2 [8][16384][64] bf16
// total = 67,777,536 B

// ---------------- prep: swizzle weights into MFMA B-fragment order ----------------
__global__ void prep_kernel(const float* __restrict__ w1, const float* __restrict__ w2,
                            const float* __restrict__ woff, const float* __restrict__ wdcn,
                            const float* __restrict__ b1, const float* __restrict__ b2,
                            const float* __restrict__ boff, const float* __restrict__ bdcn,
                            char* __restrict__ wsb) {
    bf16_t* wp1 = (bf16_t*)(wsb + WP1_B);
    bf16_t* wp2 = (bf16_t*)(wsb + WP2_B);
    bf16_t* wpo = (bf16_t*)(wsb + WPO_B);
    bf16_t* wd  = (bf16_t*)(wsb + WDCN_B);
    float*  bias= (float*)(wsb + BIAS_B);
    int tid = blockIdx.x * blockDim.x + threadIdx.x;
    int nt  = gridDim.x * blockDim.x;
    for (int i = tid; i < 25*4*4*64*8; i += nt) {
        int j = i & 7, q = i >> 3;
        int n = q % 64; q /= 64;
        int g = q & 3;  q >>= 2;
        int ck = q & 3; int t = q >> 2;
        int cin = ck*32 + g*8 + j;
        wp1[i] = (bf16_t)w1[(n*128 + cin)*25 + t];
    }
    for (int i = tid; i < 9*2*4*64*8; i += nt) {
        int j = i & 7, q = i >> 3;
        int n = q % 64; q /= 64;
        int g = q & 3;  q >>= 2;
        int ck = q & 1; int t = q >> 1;
        int cin = ck*32 + g*8 + j;
        wp2[i] = (bf16_t)w2[(n*64 + cin)*9 + t];
    }
    for (int i = tid; i < 9*2*4*32*8; i += nt) {
        int j = i & 7, q = i >> 3;
        int n = q & 31; q >>= 5;
        int g = q & 3;  q >>= 2;
        int ck = q & 1; int t = q >> 1;
        int cin = ck*32 + g*8 + j;
        wpo[i] = (n < 27) ? (bf16_t)woff[(n*64 + cin)*9 + t] : (bf16_t)0.f;
    }
    for (int i = tid; i < 18*4*4*16*8; i += nt) {
        int j = i & 7, f = i >> 3;
        int l15 = f & 15; f >>= 4;
        int l4  = f & 3;  f >>= 2;
        int ntl = f & 3;  int kc = f >> 2;
        int kg = kc*32 + l4*8 + j;
        int tap = kg >> 6, c = kg & 63;
        int n = ntl*16 + l15;
        wd[i] = (bf16_t)wdcn[n*576 + c*9 + tap];
    }
    if (tid < 64) { bias[tid] = b1[tid]; bias[64+tid] = b2[tid]; bias[160+tid] = bdcn[tid]; }
    if (tid >= 64 && tid < 96) { int n = tid - 64; bias[128+n] = (n < 27) ? boff[n] : 0.f; }
}

// ---------------- NCHW f32 (Fi||Fe) -> NHWC bf16 Xt[b][p][128] ----------------
// Fused: also writes the f32 Fi copy into Ff[:, 0:64].
__global__ __launch_bounds__(256) void nhwc_kernel(const float* __restrict__ Fi,
                                                   const float* __restrict__ Fe,
                                                   bf16_t* __restrict__ Xt,
                                                   float* __restrict__ out1) {
    __shared__ bf16_t tile[64][136];
    const int b  = blockIdx.y;
    const int p0 = blockIdx.x * 64;
    const int px = threadIdx.x & 63;
    const int csub = threadIdx.x >> 6;
    for (int ci = 0; ci < 32; ++ci) {
        int c = csub * 32 + ci;
        const float* src = (c < 64) ? (Fi + (((size_t)(b*64 + c)) << 14))
                                    : (Fe + (((size_t)(b*64 + (c-64))) << 14));
        const float v = src[p0 + px];
        tile[px][c] = (bf16_t)v;
        if (c < 64) out1[(((size_t)(b*128 + c)) << 14) + p0 + px] = v;  // Ff Fi-half (f32 NCHW)
    }
    __syncthreads();
    const int px2 = threadIdx.x >> 2;
    const int cc  = (threadIdx.x & 3) * 32;
    bf16x8* dst = (bf16x8*)(Xt + ((size_t)(b*HW) + p0 + px2) * 128 + cc);
    const bf16x8* srcl = (const bf16x8*)(&tile[px2][cc]);
    dst[0] = srcl[0]; dst[1] = srcl[1]; dst[2] = srcl[2]; dst[3] = srcl[3];
}

// ---------------- implicit-GEMM conv, wave tile 64px x 64co ----------------
// Round-0/3 geometry (proven best: round 4's MW=2 halving regressed).
template <int CIN_, int KS, int COUTP, bool LEAKY, bool OUTF32, bool OFFS>
__global__ __launch_bounds__(256) void conv_mfma(const bf16_t* __restrict__ Xt,
                                                 const bf16_t* __restrict__ Wp,
                                                 const float* __restrict__ bias,
                                                 bf16_t* __restrict__ outb,
                                                 float* __restrict__ outf,
                                                 float* __restrict__ out0) {
    constexpr int PAD = KS / 2;
    constexpr int HR  = 4 + KS - 1;        // 8 (KS=5) / 6 (KS=3)
    constexpr int HC  = 64 + KS - 1;       // 68 / 66
    constexpr int NC  = CIN_ / 32;
    constexpr int NT  = COUTP / 16;        // cout 16-tiles per wave
    __shared__ bf16_t stg[HR * HC * 40];   // 43.5 KB / 31.7 KB

    const int tid  = threadIdx.x;
    const int lane = tid & 63;
    const int wid  = tid >> 6;             // wave = output row within block
    const int b    = blockIdx.z;
    const int h0   = blockIdx.y * 4;
    const int w0   = blockIdx.x * 64;
    const int l15  = lane & 15;
    const int l4   = lane >> 4;

    f32x4 acc[4][NT];
#pragma unroll
    for (int m = 0; m < 4; ++m)
#pragma unroll
        for (int nt = 0; nt < NT; ++nt)
#pragma unroll
            for (int r = 0; r < 4; ++r) acc[m][nt][r] = 0.f;

    const bf16_t Z0 = (bf16_t)0.f;
    const bf16x8 zv = {Z0, Z0, Z0, Z0, Z0, Z0, Z0, Z0};
    const bf16x8* wpt = (const bf16x8*)Wp;

    for (int ck = 0; ck < NC; ++ck) {
        for (int s = tid; s < HR * HC; s += 256) {
            const int srow = s / HC, scol = s % HC;
            const int gh = h0 - PAD + srow, gw = w0 - PAD + scol;
            bf16x8 v0 = zv, v1 = zv, v2 = zv, v3 = zv;
            if (((unsigned)gh < 128u) && ((unsigned)gw < 128u)) {
                const bf16x8* gp = (const bf16x8*)(Xt + (((size_t)(b*HW) + (gh << 7) + gw)) * CIN_ + ck * 32);
                v0 = gp[0]; v1 = gp[1]; v2 = gp[2]; v3 = gp[3];
            }
            bf16x8* ldst = (bf16x8*)(&stg[s * 40]);
            ldst[0] = v0; ldst[1] = v1; ldst[2] = v2; ldst[3] = v3;
        }
        __syncthreads();
        int t = 0;
#pragma unroll
        for (int dy = 0; dy < KS; ++dy) {
#pragma unroll
            for (int dx = 0; dx < KS; ++dx, ++t) {
                bf16x8 a[4];
#pragma unroll
                for (int m = 0; m < 4; ++m)
                    a[m] = *(const bf16x8*)(&stg[((wid + dy) * HC + (m * 16 + l15 + dx)) * 40 + l4 * 8]);
                bf16x8 bb[NT];
#pragma unroll
                for (int nt = 0; nt < NT; ++nt)
                    bb[nt] = wpt[((size_t)((t * NC + ck) * 4 + l4)) * COUTP + nt * 16 + l15];
#pragma unroll
                for (int m = 0; m < 4; ++m)
#pragma unroll
                    for (int nt = 0; nt < NT; ++nt)
                        acc[m][nt] = __builtin_amdgcn_mfma_f32_16x16x32_bf16(a[m], bb[nt], acc[m][nt], 0, 0, 0);
            }
        }
        __syncthreads();
    }

    // epilogue: C/D 16x16: col(cout) = l15, row(px) = l4*4 + r
    const int hrow = h0 + wid;
#pragma unroll
    for (int m = 0; m < 4; ++m) {
#pragma unroll
        for (int nt = 0; nt < NT; ++nt) {
            const int n = nt * 16 + l15;
            const float bs = bias[n];
#pragma unroll
            for (int r = 0; r < 4; ++r) {
                const int px = w0 + m * 16 + l4 * 4 + r;
                float v = acc[m][nt][r] + bs;
                if (LEAKY) v = (v >= 0.f) ? v : 0.1f * v;
                const size_t pix = (size_t)(hrow << 7) + px;
                if (OUTF32) outf[(((size_t)(b * COUTP + n)) << 14) + pix] = v;         // NCHW f32
                else        outb[(((size_t)(b * HW)) + pix) * COUTP + n] = (bf16_t)v;  // NHWC bf16
                if (OFFS) {
                    if (n < 18) out0[(((size_t)(b * 18 + n)) << 14) + pix] = v;
                }
            }
        }
    }
}

// ---------------- DCNv2 via MFMA, LDS-staged bilinear gathers ----------------
// Round-6 theory: rounds 0/2/3/5 pinned dcn at ~90us regardless of occupancy,
// pipelining (compiler re-sinks loads: r5 VGPR stayed 64) and data placement.
// Arithmetic: ~37k L1-missing 64B segments per CU (footprint 25KB/wave >> 32KB
// L1) x ~400cy L2 latency / ~64-entry miss queue = ~94us. The wall is the
// per-CU L1-miss-queue x L2-latency product. Fix: stop missing L1 --
// stage the 14x14 Fe halo of an 8x8 px tile in LDS (25KB, XOR-swizzled) and
// gather via ds_read_b128. Offsets are tiny (conv outputs, 0.05-scale
// weights): |o|<2 keeps all samples in-halo; per-lane fallback to the global
// path keeps arbitrary-offset correctness (execz-skipped when untaken).
__global__ __launch_bounds__(256, 4) void dcn_mfma(const bf16_t* __restrict__ Xt,
                                                   const float* __restrict__ OO,
                                                   const bf16_t* __restrict__ Wd,
                                                   const float* __restrict__ bias,
                                                   float* __restrict__ out1) {
    __shared__ bf16_t fe[196 * 64];   // 14x14 pos x 64ch bf16, swizzled = 25088 B

    const int tid  = threadIdx.x;
    const int lane = tid & 63;
    const int wave = tid >> 6;
    const int l15  = lane & 15;
    const int l4   = lane >> 4;
    const int blk  = blockIdx.x;
    const int b    = blk & 7;                  // XCD-pinned batch
    const int tile = blk >> 3;                 // 0..255: 16x16 tiles of 8x8 px
    const int h0   = (tile >> 4) << 3;
    const int w0   = (tile & 15) << 3;
    const int r0   = h0 - 3, c0 = w0 - 3;      // halo origin

    const bf16_t Z0 = (bf16_t)0.f;
    const bf16x8 zv = {Z0, Z0, Z0, Z0, Z0, Z0, Z0, Z0};

    // ---- stage 14x14 Fe halo into LDS (swizzle: slot16B ^= (pos&7)) ----
    for (int i = tid; i < 196 * 8; i += 256) {
        const int pos = i >> 3, slot = i & 7;
        const int rr = pos / 14, cq = pos % 14;
        const int gh = r0 + rr, gw = c0 + cq;
        bf16x8 v = zv;
        if (((unsigned)gh < 128u) && ((unsigned)gw < 128u))
            v = *(const bf16x8*)(Xt + (((size_t)(b * HW) + (gh << 7) + gw)) * 128 + 64 + slot * 8);
        *(bf16x8*)(&fe[pos * 64 + ((slot * 8) ^ ((pos & 7) << 3))]) = v;
    }

    f32x4 acc[4];
#pragma unroll
    for (int nt = 0; nt < 4; ++nt) {
        const float bs = bias[nt * 16 + l15];
        acc[nt][0] = bs; acc[nt][1] = bs; acc[nt][2] = bs; acc[nt][3] = bs;
    }

    // wave's 16 px = 2 rows x 8 cols; px(i): row = h0+2*wave+(i>>3), col = w0+(i&7)
    const int prow = h0 + (wave << 1) + (l15 >> 3);
    const int pcol = w0 + (l15 & 7);
    const size_t oobase = (((size_t)(b * 32)) << 14) + (prow << 7) + pcol;

    // ---- prologue: all 27 OO loads, precompute y/x/m per tap ----
    float ys[9], xs[9], ms[9];
#pragma unroll
    for (int k = 0; k < 9; ++k) {
        const float o1v = OO[oobase + ((size_t)k << 14)];
        const float o2v = OO[oobase + ((size_t)(9 + k) << 14)];
        const float mlv = OO[oobase + ((size_t)(18 + k) << 14)];
        ys[k] = (float)(prow - 1 + (k / 3)) + o1v;
        xs[k] = (float)(pcol - 1 + (k % 3)) + o2v;
        ms[k] = 1.f / (1.f + __expf(-mlv));
    }

    const bf16_t* feb = Xt + ((size_t)(b * HW)) * 128 + 64;   // fallback path
    const bf16x8* Wdv = (const bf16x8*)Wd;

    __syncthreads();

#pragma unroll
    for (int k = 0; k < 9; ++k) {
        const float yk = ys[k], xk = xs[k];
        const float y0f = floorf(yk), x0f = floorf(xk);
        const float fy = yk - y0f, fx = xk - x0f;
        const int y0 = (int)y0f, x0 = (int)x0f;

        const bool vy0 = (unsigned)y0 < 128u;
        const bool vy1 = (unsigned)(y0 + 1) < 128u;
        const bool vx0 = (unsigned)x0 < 128u;
        const bool vx1 = (unsigned)(x0 + 1) < 128u;

        const float mk = ms[k];
        float w00 = (1.f - fy) * (1.f - fx) * mk; w00 = (vy0 && vx0) ? w00 : 0.f;
        float w01 = (1.f - fy) * fx * mk;         w01 = (vy0 && vx1) ? w01 : 0.f;
        float w10 = fy * (1.f - fx) * mk;         w10 = (vy1 && vx0) ? w10 : 0.f;
        float w11 = fy * fx * mk;                 w11 = (vy1 && vx1) ? w11 : 0.f;

        const int ry = y0 - r0, rx = x0 - c0;
        const bool inreg = ((unsigned)ry < 13u) && ((unsigned)rx < 13u);
        const int pos00 = ry * 14 + rx;

#pragma unroll
        for (int cc = 0; cc < 2; ++cc) {
            const int slot = cc * 4 + l4;
            bf16x8 v00, v01, v10, v11;
            if (inreg) {
                const int sw = slot * 8;
                v00 = *(const bf16x8*)(&fe[(pos00     ) * 64 + (sw ^ (((pos00     ) & 7) << 3))]);
                v01 = *(const bf16x8*)(&fe[(pos00 +  1) * 64 + (sw ^ (((pos00 +  1) & 7) << 3))]);
                v10 = *(const bf16x8*)(&fe[(pos00 + 14) * 64 + (sw ^ (((pos00 + 14) & 7) << 3))]);
                v11 = *(const bf16x8*)(&fe[(pos00 + 15) * 64 + (sw ^ (((pos00 + 15) & 7) << 3))]);
            } else {
                const int y0c = min(max(y0, 0), 127), y1c = min(max(y0 + 1, 0), 127);
                const int x0c = min(max(x0, 0), 127), x1c = min(max(x0 + 1, 0), 127);
                const int ch = slot * 8;
                v00 = *(const bf16x8*)(feb + ((size_t)((y0c << 7) + x0c)) * 128 + ch);
                v01 = *(const bf16x8*)(feb + ((size_t)((y0c << 7) + x1c)) * 128 + ch);
                v10 = *(const bf16x8*)(feb + ((size_t)((y1c << 7) + x0c)) * 128 + ch);
                v11 = *(const bf16x8*)(feb + ((size_t)((y1c << 7) + x1c)) * 128 + ch);
            }
            bf16x8 af;
#pragma unroll
            for (int j = 0; j < 8; ++j) {
                af[j] = (bf16_t)(w00 * (float)v00[j] + w01 * (float)v01[j]
                               + w10 * (float)v10[j] + w11 * (float)v11[j]);
            }
            const int s = k * 2 + cc;
#pragma unroll
            for (int nt = 0; nt < 4; ++nt) {
                const bf16x8 bfr = Wdv[((s * 4 + nt) * 4 + l4) * 16 + l15];
                acc[nt] = __builtin_amdgcn_mfma_f32_16x16x32_bf16(af, bfr, acc[nt], 0, 0, 0);
            }
        }
    }

    // epilogue: C row i = l4*4+r -> px(i); col = cout = nt*16+l15
#pragma unroll
    for (int nt = 0; nt < 4; ++nt) {
        const int o = nt * 16 + l15;
#pragma unroll
        for (int r = 0; r < 4; ++r) {
            const int i = l4 * 4 + r;
            const int orow = h0 + (wave << 1) + (i >> 3);
            const int ocol = w0 + (i & 7);
            out1[(((size_t)(b * 128 + 64 + o)) << 14) + (orow << 7) + ocol] = acc[nt][r];
        }
    }
}

extern "C" void kernel_launch(void* const* d_in, const int* in_sizes, int n_in,
                              void* d_out, int out_size, void* d_ws, size_t ws_size,
                              hipStream_t stream) {
    const float* Fi    = (const float*)d_in[0];
    const float* Fe    = (const float*)d_in[1];
    const float* w1    = (const float*)d_in[2];
    const float* b1    = (const float*)d_in[3];
    const float* w2    = (const float*)d_in[4];
    const float* b2    = (const float*)d_in[5];
    const float* w_off = (const float*)d_in[6];
    const float* b_off = (const float*)d_in[7];
    const float* w_dcn = (const float*)d_in[8];
    const float* b_dcn = (const float*)d_in[9];

    char* wsb = (char*)d_ws;
    bf16_t* wp1   = (bf16_t*)(wsb + WP1_B);
    bf16_t* wp2   = (bf16_t*)(wsb + WP2_B);
    bf16_t* wpo   = (bf16_t*)(wsb + WPO_B);
    bf16_t* wdcnf = (bf16_t*)(wsb + WDCN_B);
    float*  bias  = (float*)(wsb + BIAS_B);
    bf16_t* Xt    = (bf16_t*)(wsb + XT_B);
    bf16_t* feat1 = (bf16_t*)(wsb + F1_B);
    bf16_t* feat2 = (bf16_t*)(wsb + F2_B);
    float*  OO    = (float*)(wsb + F1_B);    // NCHW [b][32][HW]; alias: feat1 dead after conv2

    float* out0 = (float*)d_out;                   // offset_out [8,18,128,128]
    float* out1 = out0 + (size_t)Bn * 18 * HW;     // Ff [8,128,128,128]

    prep_kernel<<<256, 256, 0, stream>>>(w1, w2, w_off, w_dcn, b1, b2, b_off, b_dcn, wsb);

    nhwc_kernel<<<dim3(256, 8), 256, 0, stream>>>(Fi, Fe, Xt, out1);

    conv_mfma<128, 5, 64, true, false, false>
        <<<dim3(2, 32, 8), 256, 0, stream>>>(Xt, wp1, bias, feat1, nullptr, nullptr);

    conv_mfma<64, 3, 64, true, false, false>
        <<<dim3(2, 32, 8), 256, 0, stream>>>(feat1, wp2, bias + 64, feat2, nullptr, nullptr);

    conv_mfma<64, 3, 32, false, true, true>
        <<<dim3(2, 32, 8), 256, 0, stream>>>(feat2, wpo, bias + 128, nullptr, OO, out0);

    dcn_mfma<<<2048, 256, 0, stream>>>(Xt, OO, wdcnf, bias + 160, out1);
}